// Round 7
// baseline (2485.000 us; speedup 1.0000x reference)
//
#include <hip/hip_runtime.h>
#include <cstdint>
#include <cstddef>

#define NTOK 8192
#define DMODEL 1024
#define NEXP 8
#define CAP 2048
#define HFF 2730
#define HFF2 5460
#define KPAD 2752

typedef float f32x4 __attribute__((ext_vector_type(4)));
typedef __attribute__((ext_vector_type(8))) short short8;

__device__ inline unsigned short f2bf(float f) {
  union { float f; unsigned u; } v; v.f = f;
  unsigned u = v.u;
  return (unsigned short)((u + 0x7FFFu + ((u >> 16) & 1u)) >> 16);
}
__device__ inline float bf2f(unsigned short s) {
  union { unsigned u; float f; } v; v.u = ((unsigned)s) << 16; return v.f;
}

// global -> LDS direct DMA, 16 B per lane. LDS dest: wave-uniform base + lane*16.
// Global source address is PER-LANE (m173) -> swizzled staging via source permute.
typedef __attribute__((address_space(1))) const void g_void;
typedef __attribute__((address_space(3))) void l_void;
__device__ __forceinline__ void dma16(const void* g, void* l) {
  __builtin_amdgcn_global_load_lds((g_void*)g, (l_void*)l, 16, 0, 0);
}

// ---------------- cast x f32 -> bf16 (stored in d_out scratch region) ----------------
__global__ void cast_x_kernel(const float* __restrict__ x, unsigned short* __restrict__ xb) {
  size_t i = ((size_t)blockIdx.x * 256 + threadIdx.x) * 8;
  float4 v0 = *(const float4*)(x + i);
  float4 v1 = *(const float4*)(x + i + 4);
  union { short8 v; unsigned short s[8]; } p;
  p.s[0] = f2bf(v0.x); p.s[1] = f2bf(v0.y); p.s[2] = f2bf(v0.z); p.s[3] = f2bf(v0.w);
  p.s[4] = f2bf(v1.x); p.s[5] = f2bf(v1.y); p.s[6] = f2bf(v1.z); p.s[7] = f2bf(v1.w);
  *(short8*)(xb + i) = p.v;
}

// ---------------- Router: one wave per token, fp64 accumulation ----------------
__global__ void router_kernel(const float* __restrict__ x,
                              const float* __restrict__ noise,
                              const float* __restrict__ w_route,
                              const float* __restrict__ b_route,
                              const float* __restrict__ w_noise,
                              const float* __restrict__ b_noise,
                              int* __restrict__ topi,
                              float* __restrict__ gates) {
  const int lane = threadIdx.x & 63;
  const int wave = threadIdx.x >> 6;
  const int tok = blockIdx.x * 4 + wave;
  const float* xr = x + (size_t)tok * DMODEL;

  double aR[8], aN[8];
#pragma unroll
  for (int e = 0; e < 8; e++) { aR[e] = 0.0; aN[e] = 0.0; }

  for (int d = lane; d < DMODEL; d += 64) {
    double xv = (double)xr[d];
    const float* wr = w_route + d * 8;
    const float* wn = w_noise + d * 8;
#pragma unroll
    for (int e = 0; e < 8; e++) {
      aR[e] += xv * (double)wr[e];
      aN[e] += xv * (double)wn[e];
    }
  }
#pragma unroll
  for (int off = 32; off > 0; off >>= 1) {
#pragma unroll
    for (int e = 0; e < 8; e++) {
      aR[e] += __shfl_down(aR[e], (unsigned)off, 64);
      aN[e] += __shfl_down(aN[e], (unsigned)off, 64);
    }
  }
  if (lane == 0) {
    double nv[8];
#pragma unroll
    for (int e = 0; e < 8; e++) {
      double lg = aR[e] + (double)b_route[e];
      double ns = aN[e] + (double)b_noise[e];
      double sp = fmax(ns, 0.0) + log1p(exp(-fabs(ns)));  // stable softplus
      nv[e] = lg + (double)noise[(size_t)tok * 8 + e] * sp;
    }
    int i0 = 0;
#pragma unroll
    for (int e = 1; e < 8; e++) if (nv[e] > nv[i0]) i0 = e;
    int i1 = (i0 == 0) ? 1 : 0;
#pragma unroll
    for (int e = 0; e < 8; e++) if (e != i0 && nv[e] > nv[i1]) i1 = e;
    double r = exp(nv[i1] - nv[i0]);
    float g0 = (float)(1.0 / (1.0 + r));
    float g1 = (float)(r / (1.0 + r));
    topi[tok * 2] = i0; topi[tok * 2 + 1] = i1;
    gates[tok * 2] = g0; gates[tok * 2 + 1] = g1;
  }
}

// ---------------- Aux loss ----------------
__global__ void aux_kernel(const int* __restrict__ topi,
                           const float* __restrict__ gates,
                           float* __restrict__ out) {
  const int t = threadIdx.x;
  float s[8];
#pragma unroll
  for (int e = 0; e < 8; e++) s[e] = 0.f;
  for (int i = t; i < NTOK; i += 256) {
    int i0 = topi[2 * i], i1 = topi[2 * i + 1];
    float g0 = gates[2 * i], g1 = gates[2 * i + 1];
#pragma unroll
    for (int e = 0; e < 8; e++)
      s[e] += (i0 == e ? g0 : 0.f) + (i1 == e ? g1 : 0.f);
  }
  __shared__ float sh[256][8];
#pragma unroll
  for (int e = 0; e < 8; e++) sh[t][e] = s[e];
  __syncthreads();
  for (int stride = 128; stride > 0; stride >>= 1) {
    if (t < stride) {
#pragma unroll
      for (int e = 0; e < 8; e++) sh[t][e] += sh[t + stride][e];
    }
    __syncthreads();
  }
  if (t == 0) {
    float aux = 0.f;
#pragma unroll
    for (int e = 0; e < 8; e++) {
      float p = sh[0][e] / (float)NTOK - 0.125f;
      aux += p * p;
    }
    out[(size_t)NTOK * DMODEL] = aux;
  }
}

// ---------------- Dispatch: per-expert ordered capacity scan + slot map ----------------
__global__ void dispatch_kernel(const int* __restrict__ topi,
                                const float* __restrict__ gates,
                                int* __restrict__ sel,
                                float* __restrict__ gsel,
                                int* __restrict__ slot) {
  const int e = blockIdx.x;
  const int t = threadIdx.x;
  const int lane = t & 63;
  const int w = t >> 6;
  __shared__ int waveCnt[16];
  __shared__ int runningS;
  if (t == 0) runningS = 0;
  __syncthreads();

  for (int base = 0; base < NTOK; base += 1024) {
    int tok = base + t;
    int i0 = topi[2 * tok], i1 = topi[2 * tok + 1];
    bool hit = (i0 == e) || (i1 == e);
    int kth = (i0 == e) ? 0 : 1;
    float g = gates[2 * tok + kth];
    unsigned long long m = __ballot(hit);
    int prefix = __popcll(m & ((1ull << lane) - 1ull));
    if (lane == 63) waveCnt[w] = prefix + (hit ? 1 : 0);
    __syncthreads();
    int off = runningS;
    for (int ww = 0; ww < w; ww++) off += waveCnt[ww];
    int pos = off + prefix;
    if (hit) {
      if (pos < CAP) {
        sel[e * CAP + pos] = tok; gsel[e * CAP + pos] = g;
        slot[2 * tok + kth] = pos;
      } else {
        slot[2 * tok + kth] = -1;
      }
    }
    __syncthreads();
    if (t == 0) {
      int sacc = 0;
#pragma unroll
      for (int ww = 0; ww < 16; ww++) sacc += waveCnt[ww];
      runningS += sacc;
    }
    __syncthreads();
  }
  for (int p = runningS + t; p < CAP; p += 1024) { sel[e * CAP + p] = 0; gsel[e * CAP + p] = 0.f; }
}

// ---------------- Transpose wp [E][1024][5460] f32 -> wpT [E][5460][1024] bf16 ----------------
// v2: 64x64 tile, f-major LDS (pad 68 -> 8B-aligned col reads), 16B stores = 128B segments.
__global__ void transpose_wp_kernel(const float* __restrict__ wp,
                                    unsigned short* __restrict__ wpT) {
  const int e = blockIdx.z, d0 = blockIdx.y * 64, f0 = blockIdx.x * 64;
  __shared__ unsigned short tile[64][68];   // [f_local][d_local]
  const int t = threadIdx.x;
  const int ld = t >> 4;           // 0..15
  const int lf4 = (t & 15) * 4;    // 0..60
#pragma unroll
  for (int p = 0; p < 4; p++) {
    int d = d0 + p * 16 + ld;
    int f = f0 + lf4;
    if (f < HFF2) {   // HFF2 % 4 == 0, so f<HFF2 implies f+3<HFF2
      float4 v = *(const float4*)(wp + ((size_t)e * DMODEL + d) * HFF2 + f);
      tile[lf4 + 0][p * 16 + ld] = f2bf(v.x);
      tile[lf4 + 1][p * 16 + ld] = f2bf(v.y);
      tile[lf4 + 2][p * 16 + ld] = f2bf(v.z);
      tile[lf4 + 3][p * 16 + ld] = f2bf(v.w);
    }
  }
  __syncthreads();
  const int dq = (t & 7) * 8;      // 0..56
#pragma unroll
  for (int q = 0; q < 2; q++) {
    int fl = q * 32 + (t >> 3);    // 0..63
    int f = f0 + fl;
    if (f < HFF2) {
      ushort4 u0 = *(const ushort4*)&tile[fl][dq];
      ushort4 u1 = *(const ushort4*)&tile[fl][dq + 4];
      union { ushort4 u[2]; short8 v; } pk;
      pk.u[0] = u0; pk.u[1] = u1;
      *(short8*)(wpT + (size_t)e * HFF2 * DMODEL + (size_t)f * DMODEL + d0 + dq) = pk.v;
    }
  }
}

// ---------------- Transpose wd [E][2730][1024] f32 -> wdT [E][1024][2752] bf16 ----------------
__global__ void transpose_wd_kernel(const float* __restrict__ wd,
                                    unsigned short* __restrict__ wdT) {
  const int e = blockIdx.z, d0 = blockIdx.y * 32, k0 = blockIdx.x * 32;
  __shared__ unsigned short tile[32][33];
  const int t = threadIdx.x;
  {
    int lk = t >> 3, ld4 = (t & 7) * 4;
    int k = k0 + lk;
    if (k < HFF) {
      float4 v = *(const float4*)(wd + (size_t)e * HFF * DMODEL + (size_t)k * DMODEL + d0 + ld4);
      tile[lk][ld4 + 0] = f2bf(v.x);
      tile[lk][ld4 + 1] = f2bf(v.y);
      tile[lk][ld4 + 2] = f2bf(v.z);
      tile[lk][ld4 + 3] = f2bf(v.w);
    } else {
      tile[lk][ld4 + 0] = 0; tile[lk][ld4 + 1] = 0;
      tile[lk][ld4 + 2] = 0; tile[lk][ld4 + 3] = 0;
    }
  }
  __syncthreads();
  {
    int ld = t >> 3, lkq = (t & 7) * 4;
    ushort4 o = make_ushort4(tile[lkq + 0][ld], tile[lkq + 1][ld],
                             tile[lkq + 2][ld], tile[lkq + 3][ld]);
    *(ushort4*)(wdT + (size_t)e * DMODEL * KPAD + (size_t)(d0 + ld) * KPAD + k0 + lkq) = o;
  }
}

// ---------------- GEMM1: h = silu(X@wp1)*(X@wp2) ----------------
// Barrier-free per-wave pipeline, v2 (R6 resubmit with clamped B rows):
//  - A: DIRECT global->reg fragments (wave-private rows, zero redundancy),
//    double-buffered one tile ahead.
//  - B: per-wave private 2-deep LDS ring (2 x 8 KB), swizzled stage/read
//    (R1's proven pair -> 2-way max = free).
//  - 64 KB LDS/block -> 2 blocks/CU -> 2 waves/SIMD: LDS reads and MFMA of
//    different waves overlap on each SIMD.
//  - Per tile per wave: 8 B-dma + 8 A-loads -> uniform vmcnt(16) guards B(kt).
__global__ __launch_bounds__(256, 2)
void gemm1_kernel(const unsigned short* __restrict__ xb,
                  const unsigned short* __restrict__ wpT,
                  const int* __restrict__ sel,
                  unsigned short* __restrict__ h) {
  const int e = blockIdx.z;
  const int m0 = blockIdx.x * 512;
  const int n0 = blockIdx.y * 64;                 // per SwiGLU half

  __shared__ __align__(16) unsigned short smem[32768];   // 4 waves x 2 bufs x 8 KB

  const int t = threadIdx.x;
  const int lane = t & 63;
  const int w = t >> 6;          // 0..3
  const int fr = lane & 15;
  const int fq = lane >> 4;
  const int lr = lane >> 2;      // staging row-within-group 0..15
  const int lks = ((lane & 3) ^ ((lane >> 3) & 3)) * 8;          // swizzled source chunk (elems)
  const int rb = fr * 64 + (fq ^ ((fr >> 1) & 3)) * 16;          // swizzled read byte offset

  // A: direct-to-fragment pointers. lane (fr,fq) of frag i holds xb[tok][k0+fq*8 ..+8]
  const unsigned short* aSrc[8];
#pragma unroll
  for (int i = 0; i < 8; i++) {
    int tok = sel[e * CAP + m0 + w * 128 + i * 16 + fr];
    aSrc[i] = xb + (size_t)tok * DMODEL + fq * 8;
  }
  // B staging row pointers, clamped to HFF-1 (dup rows; cols zeroed in epilogue)
  const unsigned short* bSrc1[4];
  const unsigned short* bSrc2[4];
#pragma unroll
  for (int j = 0; j < 4; j++) {
    int c = n0 + j * 16 + lr; if (c >= HFF) c = HFF - 1;
    bSrc1[j] = wpT + ((size_t)e * HFF2 + c) * DMODEL + lks;
    bSrc2[j] = wpT + ((size_t)e * HFF2 + HFF + c) * DMODEL + lks;
  }

  char* myLds = (char*)smem + w * 16384;

  auto stageB = [&](int kt) {
    char* buf = myLds + (kt & 1) * 8192;
    const int k0 = kt * 32;
#pragma unroll
    for (int j = 0; j < 4; j++) {
      dma16(bSrc1[j] + k0, buf + j * 1024);
      dma16(bSrc2[j] + k0, buf + 4096 + j * 1024);
    }
  };

  f32x4 acc1[8][4], acc2[8][4];
#pragma unroll
  for (int i = 0; i < 8; i++)
#pragma unroll
    for (int j = 0; j < 4; j++) { acc1[i][j] = (f32x4)0.f; acc2[i][j] = (f32x4)0.f; }

  short8 aA[8], aB[8];
  stageB(0);                                   // 8 dma
#pragma unroll
  for (int i = 0; i < 8; i++) aA[i] = *(const short8*)(aSrc[i]);   // A(0): 8 loads
  stageB(1);                                   // 8 dma

  auto step = [&](int kt, short8 (&aC)[8], short8 (&aN)[8]) {
    // B(kt) resident: the 16 newer VMEM ops (A(kt), B(kt+1)) may be in flight
    asm volatile("s_waitcnt vmcnt(16)" ::: "memory");
    const char* buf = (const char*)myLds + (kt & 1) * 8192;
    short8 b1[4], b2[4];
#pragma unroll
    for (int j = 0; j < 4; j++) {
      b1[j] = *(const short8*)(buf + j * 1024 + rb);
      b2[j] = *(const short8*)(buf + 4096 + j * 1024 + rb);
    }
    asm volatile("s_waitcnt lgkmcnt(0)" ::: "memory");   // reads landed; buffer reusable
    if (kt < 30) stageB(kt + 2);
    if (kt < 31) {
      const int k1 = (kt + 1) * 32;
#pragma unroll
      for (int i = 0; i < 8; i++) aN[i] = *(const short8*)(aSrc[i] + k1);
    }
#pragma unroll
    for (int i = 0; i < 8; i++)
#pragma unroll
      for (int j = 0; j < 4; j++) {
        acc1[i][j] = __builtin_amdgcn_mfma_f32_16x16x32_bf16(aC[i], b1[j], acc1[i][j], 0, 0, 0);
        acc2[i][j] = __builtin_amdgcn_mfma_f32_16x16x32_bf16(aC[i], b2[j], acc2[i][j], 0, 0, 0);
      }
  };

  for (int kt = 0; kt < 32; kt += 2) { step(kt, aA, aB); step(kt + 1, aB, aA); }

#pragma unroll
  for (int i = 0; i < 8; i++) {
#pragma unroll
    for (int j = 0; j < 4; j++) {
      const int col = n0 + j * 16 + fr;
#pragma unroll
      for (int r = 0; r < 4; r++) {
        const int row = m0 + w * 128 + i * 16 + fq * 4 + r;
        float v1 = acc1[i][j][r], v2 = acc2[i][j][r];
        float hv = (col < HFF) ? (v1 / (1.f + __expf(-v1))) * v2 : 0.f;
        h[((size_t)e * CAP + row) * KPAD + col] = f2bf(hv);
      }
    }
  }
}

// ---------------- GEMM2: contrib[e][slot] = h @ wd ----------------
// Same v2 structure: A-direct (reg-dbuf), B-only per-wave LDS ring, swizzled.
// 4 waves x (M=128, N=128); grid (4,8,8)=256 blocks. 86 K-tiles.
__global__ __launch_bounds__(256, 1)
void gemm2_kernel(const unsigned short* __restrict__ h,
                  const unsigned short* __restrict__ wdT,
                  unsigned short* __restrict__ contrib) {
  const int e = blockIdx.z;
  const int m0 = blockIdx.x * 512;
  const int n0 = blockIdx.y * 128;

  __shared__ __align__(16) unsigned short smem[32768];   // 4 waves x 2 bufs x 8 KB

  const int t = threadIdx.x;
  const int lane = t & 63;
  const int w = t >> 6;
  const int fr = lane & 15;
  const int fq = lane >> 4;
  const int lr = lane >> 2;
  const int lks = ((lane & 3) ^ ((lane >> 3) & 3)) * 8;
  const int rb = fr * 64 + (fq ^ ((fr >> 1) & 3)) * 16;

  const unsigned short* aSrc[8];
#pragma unroll
  for (int i = 0; i < 8; i++)
    aSrc[i] = h + ((size_t)e * CAP + m0 + w * 128 + i * 16 + fr) * KPAD + fq * 8;
  const unsigned short* bBase = wdT + ((size_t)e * DMODEL + n0 + lr) * KPAD + lks;

  char* myLds = (char*)smem + w * 16384;

  auto stageB = [&](int kt) {
    char* buf = myLds + (kt & 1) * 8192;
    const int k0 = kt * 32;
#pragma unroll
    for (int j = 0; j < 8; j++)
      dma16(bBase + (size_t)j * 16 * KPAD + k0, buf + j * 1024);
  };

  f32x4 acc[8][8];
#pragma unroll
  for (int i = 0; i < 8; i++)
#pragma unroll
    for (int j = 0; j < 8; j++) acc[i][j] = (f32x4)0.f;

  short8 aA[8], aB[8];
  stageB(0);
#pragma unroll
  for (int i = 0; i < 8; i++) aA[i] = *(const short8*)(aSrc[i]);
  stageB(1);

  auto step = [&](int kt, short8 (&aC)[8], short8 (&aN)[8]) {
    asm volatile("s_waitcnt vmcnt(16)" ::: "memory");
    const char* buf = (const char*)myLds + (kt & 1) * 8192;
    short8 b[8];
#pragma unroll
    for (int j = 0; j < 8; j++)
      b[j] = *(const short8*)(buf + j * 1024 + rb);
    asm volatile("s_waitcnt lgkmcnt(0)" ::: "memory");
    if (kt < 84) stageB(kt + 2);
    if (kt < 85) {
      const int k1 = (kt + 1) * 32;
#pragma unroll
      for (int i = 0; i < 8; i++) aN[i] = *(const short8*)(aSrc[i] + k1);
    }
#pragma unroll
    for (int i = 0; i < 8; i++)
#pragma unroll
      for (int j = 0; j < 8; j++)
        acc[i][j] = __builtin_amdgcn_mfma_f32_16x16x32_bf16(aC[i], b[j], acc[i][j], 0, 0, 0);
  };

  for (int kt = 0; kt < 86; kt += 2) { step(kt, aA, aB); step(kt + 1, aB, aA); }

#pragma unroll
  for (int i = 0; i < 8; i++) {
#pragma unroll
    for (int j = 0; j < 8; j++) {
      const int col = n0 + j * 16 + fr;
#pragma unroll
      for (int r = 0; r < 4; r++) {
        const int row = m0 + w * 128 + i * 16 + fq * 4 + r;
        contrib[((size_t)e * CAP + row) * DMODEL + col] = f2bf(acc[i][j][r]);
      }
    }
  }
}

// ---------------- Combine: out[tok] = g0*contrib[e0][s0] + g1*contrib[e1][s1] ----------------
__global__ void combine_kernel(const unsigned short* __restrict__ contrib,
                               const int* __restrict__ topi,
                               const int* __restrict__ slot,
                               const float* __restrict__ gates,
                               float* __restrict__ out) {
  const int tok = blockIdx.x;
  const int t = threadIdx.x;
  const int e0 = topi[2 * tok], e1 = topi[2 * tok + 1];
  const int s0 = slot[2 * tok], s1 = slot[2 * tok + 1];
  const float g0 = gates[2 * tok], g1 = gates[2 * tok + 1];
  float4 acc = make_float4(0.f, 0.f, 0.f, 0.f);
  if (s0 >= 0) {
    ushort4 c = *(const ushort4*)(contrib + ((size_t)(e0 * CAP + s0)) * DMODEL + t * 4);
    acc.x += g0 * bf2f(c.x); acc.y += g0 * bf2f(c.y);
    acc.z += g0 * bf2f(c.z); acc.w += g0 * bf2f(c.w);
  }
  if (s1 >= 0) {
    ushort4 c = *(const ushort4*)(contrib + ((size_t)(e1 * CAP + s1)) * DMODEL + t * 4);
    acc.x += g1 * bf2f(c.x); acc.y += g1 * bf2f(c.y);
    acc.z += g1 * bf2f(c.z); acc.w += g1 * bf2f(c.w);
  }
  *(float4*)(out + (size_t)tok * DMODEL + t * 4) = acc;
}

// ---------------- launch ----------------
extern "C" void kernel_launch(void* const* d_in, const int* in_sizes, int n_in,
                              void* d_out, int out_size, void* d_ws, size_t ws_size,
                              hipStream_t stream) {
  const float* x = (const float*)d_in[0];
  const float* noise = (const float*)d_in[1];
  const float* w_route = (const float*)d_in[2];
  const float* b_route = (const float*)d_in[3];
  const float* w_noise = (const float*)d_in[4];
  const float* b_noise = (const float*)d_in[5];
  const float* w_proj = (const float*)d_in[6];
  const float* w_down = (const float*)d_in[7];
  float* out = (float*)d_out;

  char* ws = (char*)d_ws;
  const size_t WT_BYTES = (size_t)NEXP * HFF2 * DMODEL * 2;   // 89.4 MB (wpT; later wdT+contrib)
  const size_t WDT_BYTES = (size_t)NEXP * DMODEL * KPAD * 2;  // 45.1 MB
  const size_t H_BYTES = (size_t)NEXP * CAP * KPAD * 2;       // 90.2 MB
  unsigned short* wT = (unsigned short*)ws;
  unsigned short* contrib = (unsigned short*)(ws + WDT_BYTES);  // 33.5 MB, dead tail of wT region
  unsigned short* hbuf = (unsigned short*)(ws + WT_BYTES);
  char* p = ws + WT_BYTES + H_BYTES;
  int* sel = (int*)p;          p += (size_t)NEXP * CAP * 4;
  float* gsel = (float*)p;     p += (size_t)NEXP * CAP * 4;
  int* topi = (int*)p;         p += (size_t)NTOK * 2 * 4;
  float* gates = (float*)p;    p += (size_t)NTOK * 2 * 4;
  int* slot = (int*)p;

  // xb (bf16 x, 16.8 MB) lives in d_out until gemm1 done; combine overwrites out fully.
  unsigned short* xb = (unsigned short*)d_out;

  hipLaunchKernelGGL(cast_x_kernel, dim3(NTOK * DMODEL / (256 * 8)), dim3(256), 0, stream, x, xb);
  hipLaunchKernelGGL(router_kernel, dim3(NTOK / 4), dim3(256), 0, stream,
                     x, noise, w_route, b_route, w_noise, b_noise, topi, gates);
  hipLaunchKernelGGL(dispatch_kernel, dim3(NEXP), dim3(1024), 0, stream, topi, gates, sel, gsel, slot);
  hipLaunchKernelGGL(transpose_wp_kernel, dim3(86, 16, NEXP), dim3(256), 0, stream, w_proj, wT);
  hipLaunchKernelGGL(gemm1_kernel, dim3(CAP / 512, KPAD / 64, NEXP), dim3(256), 0, stream,
                     xb, wT, sel, hbuf);
  hipLaunchKernelGGL(transpose_wd_kernel, dim3(KPAD / 32, DMODEL / 32, NEXP), dim3(256), 0, stream, w_down, wT);
  hipLaunchKernelGGL(gemm2_kernel, dim3(CAP / 512, DMODEL / 128, NEXP), dim3(256), 0, stream,
                     hbuf, wT, contrib);
  hipLaunchKernelGGL(combine_kernel, dim3(NTOK), dim3(256), 0, stream,
                     contrib, topi, slot, gates, out);
  hipLaunchKernelGGL(aux_kernel, dim3(1), dim3(256), 0, stream, topi, gates, out);
}

// Round 8
// 785.826 us; speedup vs baseline: 3.1623x; 3.1623x over previous
//
#include <hip/hip_runtime.h>
#include <cstdint>
#include <cstddef>

#define NTOK 8192
#define DMODEL 1024
#define NEXP 8
#define CAP 2048
#define HFF 2730
#define HFF2 5460
#define KPAD 2752

typedef float f32x4 __attribute__((ext_vector_type(4)));
typedef __attribute__((ext_vector_type(8))) short short8;

__device__ inline unsigned short f2bf(float f) {
  union { float f; unsigned u; } v; v.f = f;
  unsigned u = v.u;
  return (unsigned short)((u + 0x7FFFu + ((u >> 16) & 1u)) >> 16);
}
__device__ inline float bf2f(unsigned short s) {
  union { unsigned u; float f; } v; v.u = ((unsigned)s) << 16; return v.f;
}

// global -> LDS direct DMA, 16 B per lane. LDS dest: wave-uniform base + lane*16.
typedef __attribute__((address_space(1))) const void g_void;
typedef __attribute__((address_space(3))) void l_void;
__device__ __forceinline__ void dma16(const void* g, void* l) {
  __builtin_amdgcn_global_load_lds((g_void*)g, (l_void*)l, 16, 0, 0);
}

// ---------------- cast x f32 -> bf16 (stored in d_out scratch region) ----------------
__global__ void cast_x_kernel(const float* __restrict__ x, unsigned short* __restrict__ xb) {
  size_t i = ((size_t)blockIdx.x * 256 + threadIdx.x) * 8;
  float4 v0 = *(const float4*)(x + i);
  float4 v1 = *(const float4*)(x + i + 4);
  union { short8 v; unsigned short s[8]; } p;
  p.s[0] = f2bf(v0.x); p.s[1] = f2bf(v0.y); p.s[2] = f2bf(v0.z); p.s[3] = f2bf(v0.w);
  p.s[4] = f2bf(v1.x); p.s[5] = f2bf(v1.y); p.s[6] = f2bf(v1.z); p.s[7] = f2bf(v1.w);
  *(short8*)(xb + i) = p.v;
}

// ---------------- Router: one wave per token, fp64 accumulation ----------------
__global__ void router_kernel(const float* __restrict__ x,
                              const float* __restrict__ noise,
                              const float* __restrict__ w_route,
                              const float* __restrict__ b_route,
                              const float* __restrict__ w_noise,
                              const float* __restrict__ b_noise,
                              int* __restrict__ topi,
                              float* __restrict__ gates) {
  const int lane = threadIdx.x & 63;
  const int wave = threadIdx.x >> 6;
  const int tok = blockIdx.x * 4 + wave;
  const float* xr = x + (size_t)tok * DMODEL;

  double aR[8], aN[8];
#pragma unroll
  for (int e = 0; e < 8; e++) { aR[e] = 0.0; aN[e] = 0.0; }

  for (int d = lane; d < DMODEL; d += 64) {
    double xv = (double)xr[d];
    const float* wr = w_route + d * 8;
    const float* wn = w_noise + d * 8;
#pragma unroll
    for (int e = 0; e < 8; e++) {
      aR[e] += xv * (double)wr[e];
      aN[e] += xv * (double)wn[e];
    }
  }
#pragma unroll
  for (int off = 32; off > 0; off >>= 1) {
#pragma unroll
    for (int e = 0; e < 8; e++) {
      aR[e] += __shfl_down(aR[e], (unsigned)off, 64);
      aN[e] += __shfl_down(aN[e], (unsigned)off, 64);
    }
  }
  if (lane == 0) {
    double nv[8];
#pragma unroll
    for (int e = 0; e < 8; e++) {
      double lg = aR[e] + (double)b_route[e];
      double ns = aN[e] + (double)b_noise[e];
      double sp = fmax(ns, 0.0) + log1p(exp(-fabs(ns)));  // stable softplus
      nv[e] = lg + (double)noise[(size_t)tok * 8 + e] * sp;
    }
    int i0 = 0;
#pragma unroll
    for (int e = 1; e < 8; e++) if (nv[e] > nv[i0]) i0 = e;
    int i1 = (i0 == 0) ? 1 : 0;
#pragma unroll
    for (int e = 0; e < 8; e++) if (e != i0 && nv[e] > nv[i1]) i1 = e;
    double r = exp(nv[i1] - nv[i0]);
    float g0 = (float)(1.0 / (1.0 + r));
    float g1 = (float)(r / (1.0 + r));
    topi[tok * 2] = i0; topi[tok * 2 + 1] = i1;
    gates[tok * 2] = g0; gates[tok * 2 + 1] = g1;
  }
}

// ---------------- Aux loss ----------------
__global__ void aux_kernel(const int* __restrict__ topi,
                           const float* __restrict__ gates,
                           float* __restrict__ out) {
  const int t = threadIdx.x;
  float s[8];
#pragma unroll
  for (int e = 0; e < 8; e++) s[e] = 0.f;
  for (int i = t; i < NTOK; i += 256) {
    int i0 = topi[2 * i], i1 = topi[2 * i + 1];
    float g0 = gates[2 * i], g1 = gates[2 * i + 1];
#pragma unroll
    for (int e = 0; e < 8; e++)
      s[e] += (i0 == e ? g0 : 0.f) + (i1 == e ? g1 : 0.f);
  }
  __shared__ float sh[256][8];
#pragma unroll
  for (int e = 0; e < 8; e++) sh[t][e] = s[e];
  __syncthreads();
  for (int stride = 128; stride > 0; stride >>= 1) {
    if (t < stride) {
#pragma unroll
      for (int e = 0; e < 8; e++) sh[t][e] += sh[t + stride][e];
    }
    __syncthreads();
  }
  if (t == 0) {
    float aux = 0.f;
#pragma unroll
    for (int e = 0; e < 8; e++) {
      float p = sh[0][e] / (float)NTOK - 0.125f;
      aux += p * p;
    }
    out[(size_t)NTOK * DMODEL] = aux;
  }
}

// ---------------- Dispatch: per-expert ordered capacity scan + slot map ----------------
__global__ void dispatch_kernel(const int* __restrict__ topi,
                                const float* __restrict__ gates,
                                int* __restrict__ sel,
                                float* __restrict__ gsel,
                                int* __restrict__ slot) {
  const int e = blockIdx.x;
  const int t = threadIdx.x;
  const int lane = t & 63;
  const int w = t >> 6;
  __shared__ int waveCnt[16];
  __shared__ int runningS;
  if (t == 0) runningS = 0;
  __syncthreads();

  for (int base = 0; base < NTOK; base += 1024) {
    int tok = base + t;
    int i0 = topi[2 * tok], i1 = topi[2 * tok + 1];
    bool hit = (i0 == e) || (i1 == e);
    int kth = (i0 == e) ? 0 : 1;
    float g = gates[2 * tok + kth];
    unsigned long long m = __ballot(hit);
    int prefix = __popcll(m & ((1ull << lane) - 1ull));
    if (lane == 63) waveCnt[w] = prefix + (hit ? 1 : 0);
    __syncthreads();
    int off = runningS;
    for (int ww = 0; ww < w; ww++) off += waveCnt[ww];
    int pos = off + prefix;
    if (hit) {
      if (pos < CAP) {
        sel[e * CAP + pos] = tok; gsel[e * CAP + pos] = g;
        slot[2 * tok + kth] = pos;
      } else {
        slot[2 * tok + kth] = -1;
      }
    }
    __syncthreads();
    if (t == 0) {
      int sacc = 0;
#pragma unroll
      for (int ww = 0; ww < 16; ww++) sacc += waveCnt[ww];
      runningS += sacc;
    }
    __syncthreads();
  }
  for (int p = runningS + t; p < CAP; p += 1024) { sel[e * CAP + p] = 0; gsel[e * CAP + p] = 0.f; }
}

// ---------------- Transpose wp [E][1024][5460] f32 -> wpT [E][5460][1024] bf16 ----------------
// v2: 64x64 tile, f-major LDS (pad 68 -> 8B-aligned col reads), 16B stores = 128B segments.
__global__ void transpose_wp_kernel(const float* __restrict__ wp,
                                    unsigned short* __restrict__ wpT) {
  const int e = blockIdx.z, d0 = blockIdx.y * 64, f0 = blockIdx.x * 64;
  __shared__ unsigned short tile[64][68];   // [f_local][d_local]
  const int t = threadIdx.x;
  const int ld = t >> 4;           // 0..15
  const int lf4 = (t & 15) * 4;    // 0..60
#pragma unroll
  for (int p = 0; p < 4; p++) {
    int d = d0 + p * 16 + ld;
    int f = f0 + lf4;
    if (f < HFF2) {   // HFF2 % 4 == 0, so f<HFF2 implies f+3<HFF2
      float4 v = *(const float4*)(wp + ((size_t)e * DMODEL + d) * HFF2 + f);
      tile[lf4 + 0][p * 16 + ld] = f2bf(v.x);
      tile[lf4 + 1][p * 16 + ld] = f2bf(v.y);
      tile[lf4 + 2][p * 16 + ld] = f2bf(v.z);
      tile[lf4 + 3][p * 16 + ld] = f2bf(v.w);
    }
  }
  __syncthreads();
  const int dq = (t & 7) * 8;      // 0..56
#pragma unroll
  for (int q = 0; q < 2; q++) {
    int fl = q * 32 + (t >> 3);    // 0..63
    int f = f0 + fl;
    if (f < HFF2) {
      ushort4 u0 = *(const ushort4*)&tile[fl][dq];
      ushort4 u1 = *(const ushort4*)&tile[fl][dq + 4];
      union { ushort4 u[2]; short8 v; } pk;
      pk.u[0] = u0; pk.u[1] = u1;
      *(short8*)(wpT + (size_t)e * HFF2 * DMODEL + (size_t)f * DMODEL + d0 + dq) = pk.v;
    }
  }
}

// ---------------- Transpose wd [E][2730][1024] f32 -> wdT [E][1024][2752] bf16 ----------------
__global__ void transpose_wd_kernel(const float* __restrict__ wd,
                                    unsigned short* __restrict__ wdT) {
  const int e = blockIdx.z, d0 = blockIdx.y * 32, k0 = blockIdx.x * 32;
  __shared__ unsigned short tile[32][33];
  const int t = threadIdx.x;
  {
    int lk = t >> 3, ld4 = (t & 7) * 4;
    int k = k0 + lk;
    if (k < HFF) {
      float4 v = *(const float4*)(wd + (size_t)e * HFF * DMODEL + (size_t)k * DMODEL + d0 + ld4);
      tile[lk][ld4 + 0] = f2bf(v.x);
      tile[lk][ld4 + 1] = f2bf(v.y);
      tile[lk][ld4 + 2] = f2bf(v.z);
      tile[lk][ld4 + 3] = f2bf(v.w);
    } else {
      tile[lk][ld4 + 0] = 0; tile[lk][ld4 + 1] = 0;
      tile[lk][ld4 + 2] = 0; tile[lk][ld4 + 3] = 0;
    }
  }
  __syncthreads();
  {
    int ld = t >> 3, lkq = (t & 7) * 4;
    ushort4 o = make_ushort4(tile[lkq + 0][ld], tile[lkq + 1][ld],
                             tile[lkq + 2][ld], tile[lkq + 3][ld]);
    *(ushort4*)(wdT + (size_t)e * DMODEL * KPAD + (size_t)(d0 + ld) * KPAD + k0 + lkq) = o;
  }
}

// ---------------- GEMM1: h = silu(X@wp1)*(X@wp2) ----------------
// R1 structure (best verified: 228 us, MfmaUtil 37): 8-wave, BM=256, BN=128
// per half, 4-buffer LDS ring, counted vmcnt (8/4/0), one barrier per K-tile.
// NEW: XCD-bijective remap -- the 8 m-blocks sharing one (n0,e) B-panel land
// on one XCD (L2 reuse; B-panel 512 KB << 4 MB L2). Perf heuristic only.
__global__ __launch_bounds__(512, 2)
void gemm1_kernel(const unsigned short* __restrict__ xb,
                  const unsigned short* __restrict__ wpT,
                  const int* __restrict__ sel,
                  unsigned short* __restrict__ h) {
  // XCD remap: L linear block id; group G = (e,n0); member = m-block.
  // XCD(L) ~ L%8 = r; G%8 == r so all 8 members of G share an XCD. Bijective.
  const int L = blockIdx.x + 8 * (blockIdx.y + 22 * blockIdx.z);
  const int r = L & 7, q = L >> 3;           // q in [0,176)
  const int G = (q % 22) * 8 + r;            // group in [0,176)
  const int e = G / 22;
  const int n0 = (G % 22) * 128;
  const int m0 = (q / 22) * 256;

  __shared__ __align__(16) unsigned short smem[4 * 16384];   // 128 KiB

  const int t = threadIdx.x;
  const int lane = t & 63;
  const int w = t >> 6;          // 0..7
  const int wr = w >> 2;         // 2-way M split (128 rows each)
  const int wc = w & 3;          // 4-way N split (32 cols each)
  const int fr = lane & 15;
  const int fq = lane >> 4;
  const int csw = (fq ^ ((fr >> 1) & 3)) * 8;      // swizzled read chunk (elems)

  // staging: thread t covers A rows r0 / r0+128, B1 row r0, B2 row r0
  const int r0 = t >> 2;                           // 0..127
  const int sw = ((t & 3) ^ ((t >> 3) & 3)) * 8;   // swizzled global seg (elems)
  const int tok0 = sel[e * CAP + m0 + r0];
  const int tok1 = sel[e * CAP + m0 + 128 + r0];
  const unsigned short* ga0 = xb + (size_t)tok0 * DMODEL + sw;
  const unsigned short* ga1 = xb + (size_t)tok1 * DMODEL + sw;
  const size_t ebase = (size_t)e * HFF2;
  int c0 = n0 + r0; if (c0 >= HFF) c0 = HFF - 1;   // dup rows; cols zeroed in epilogue
  const unsigned short* gb1 = wpT + (ebase + (size_t)c0) * DMODEL + sw;
  const unsigned short* gb2 = wpT + (ebase + (size_t)(HFF + c0)) * DMODEL + sw;

  const int dOff = w * 1024;     // bytes: wave-uniform LDS slice (16 rows/wave)

  f32x4 acc1[8][2], acc2[8][2];
#pragma unroll
  for (int i = 0; i < 8; i++)
#pragma unroll
    for (int j = 0; j < 2; j++) { acc1[i][j] = (f32x4)0.f; acc2[i][j] = (f32x4)0.f; }

  auto stageA = [&](int kt) {
    char* b = (char*)smem + (size_t)(kt & 3) * 32768;
    const int k0 = kt * 32;
    dma16(ga0 + k0, b + dOff);                 // A rows   0..127
    dma16(ga1 + k0, b + 8192 + dOff);          // A rows 128..255
  };
  auto stageB = [&](int kt) {
    char* b = (char*)smem + (size_t)(kt & 3) * 32768;
    const int k0 = kt * 32;
    dma16(gb1 + k0, b + 16384 + dOff);         // B1 rows 0..127
    dma16(gb2 + k0, b + 24576 + dOff);         // B2 rows 0..127
  };

  stageA(0); stageB(0); stageA(1); stageB(1); stageA(2); stageB(2);

  for (int kt = 0; kt < 32; ++kt) {
    if (kt < 30)       asm volatile("s_waitcnt vmcnt(8)" ::: "memory");
    else if (kt == 30) asm volatile("s_waitcnt vmcnt(4)" ::: "memory");
    else               asm volatile("s_waitcnt vmcnt(0)" ::: "memory");
    __builtin_amdgcn_s_barrier();
    asm volatile("" ::: "memory");   // dma16 writes invisible to alias analysis

    const unsigned short* Ab  = smem + (kt & 3) * 16384;
    const unsigned short* B1b = Ab + 8192;
    const unsigned short* B2b = Ab + 12288;
    short8 a[8], b1[2], b2[2];
#pragma unroll
    for (int i = 0; i < 8; i++)
      a[i] = *(const short8*)(Ab + (wr * 128 + i * 16 + fr) * 32 + csw);
#pragma unroll
    for (int j = 0; j < 2; j++) {
      b1[j] = *(const short8*)(B1b + (wc * 32 + j * 16 + fr) * 32 + csw);
      b2[j] = *(const short8*)(B2b + (wc * 32 + j * 16 + fr) * 32 + csw);
    }
    if (kt < 29) stageA(kt + 3);
    __builtin_amdgcn_s_setprio(1);
#pragma unroll
    for (int i = 0; i < 8; i++)
#pragma unroll
      for (int j = 0; j < 2; j++)
        acc1[i][j] = __builtin_amdgcn_mfma_f32_16x16x32_bf16(a[i], b1[j], acc1[i][j], 0, 0, 0);
    __builtin_amdgcn_s_setprio(0);
    if (kt < 29) stageB(kt + 3);
    __builtin_amdgcn_s_setprio(1);
#pragma unroll
    for (int i = 0; i < 8; i++)
#pragma unroll
      for (int j = 0; j < 2; j++)
        acc2[i][j] = __builtin_amdgcn_mfma_f32_16x16x32_bf16(a[i], b2[j], acc2[i][j], 0, 0, 0);
    __builtin_amdgcn_s_setprio(0);
  }

#pragma unroll
  for (int i = 0; i < 8; i++) {
#pragma unroll
    for (int j = 0; j < 2; j++) {
      const int col = n0 + wc * 32 + j * 16 + fr;
      if (col < KPAD) {
#pragma unroll
        for (int r2 = 0; r2 < 4; r2++) {
          const int row = m0 + wr * 128 + i * 16 + fq * 4 + r2;
          float v1 = acc1[i][j][r2], v2 = acc2[i][j][r2];
          float hv = (col < HFF) ? (v1 / (1.f + __expf(-v1))) * v2 : 0.f;
          h[((size_t)e * CAP + row) * KPAD + col] = f2bf(hv);
        }
      }
    }
  }
}

// ---------------- GEMM2: contrib[e][slot] = h @ wd ----------------
// R1 structure + XCD-bijective remap (8 m-blocks of one (e,n0) B-panel per XCD).
__global__ __launch_bounds__(512, 2)
void gemm2_kernel(const unsigned short* __restrict__ h,
                  const unsigned short* __restrict__ wdT,
                  unsigned short* __restrict__ contrib) {
  const int L = blockIdx.x + 8 * (blockIdx.y + 4 * blockIdx.z);   // [0,256)
  const int r = L & 7, q = L >> 3;           // q in [0,32)
  const int G = (q % 4) * 8 + r;             // group in [0,32)
  const int e = G / 4;
  const int n0 = (G % 4) * 256;
  const int m0 = (q / 4) * 256;

  __shared__ __align__(16) unsigned short smem[4 * 16384];   // 128 KiB

  const int t = threadIdx.x;
  const int lane = t & 63;
  const int w = t >> 6;
  const int wr = w >> 2;         // 2-way M split (128 rows)
  const int wc = w & 3;          // 4-way N split (64 cols)
  const int fr = lane & 15;
  const int fq = lane >> 4;
  const int csw = (fq ^ ((fr >> 1) & 3)) * 8;

  const int r0 = t >> 2;
  const int sw = ((t & 3) ^ ((t >> 3) & 3)) * 8;
  const unsigned short* ga0 = h + ((size_t)e * CAP + m0 + r0) * KPAD + sw;
  const unsigned short* ga1 = h + ((size_t)e * CAP + m0 + 128 + r0) * KPAD + sw;
  const unsigned short* gb0 = wdT + ((size_t)e * DMODEL + n0 + r0) * KPAD + sw;
  const unsigned short* gb1 = wdT + ((size_t)e * DMODEL + n0 + 128 + r0) * KPAD + sw;

  const int dOff = w * 1024;

  f32x4 acc[8][4];
#pragma unroll
  for (int i = 0; i < 8; i++)
#pragma unroll
    for (int j = 0; j < 4; j++) acc[i][j] = (f32x4)0.f;

  auto stageA = [&](int kt) {
    char* b = (char*)smem + (size_t)(kt & 3) * 32768;
    const int k0 = kt * 32;
    dma16(ga0 + k0, b + dOff);                 // A rows   0..127
    dma16(ga1 + k0, b + 8192 + dOff);          // A rows 128..255
  };
  auto stageB = [&](int kt) {
    char* b = (char*)smem + (size_t)(kt & 3) * 32768;
    const int k0 = kt * 32;
    dma16(gb0 + k0, b + 16384 + dOff);         // B rows   0..127
    dma16(gb1 + k0, b + 24576 + dOff);         // B rows 128..255
  };

  stageA(0); stageB(0); stageA(1); stageB(1); stageA(2); stageB(2);

  for (int kt = 0; kt < 86; ++kt) {
    if (kt < 84)       asm volatile("s_waitcnt vmcnt(8)" ::: "memory");
    else if (kt == 84) asm volatile("s_waitcnt vmcnt(4)" ::: "memory");
    else               asm volatile("s_waitcnt vmcnt(0)" ::: "memory");
    __builtin_amdgcn_s_barrier();
    asm volatile("" ::: "memory");

    const unsigned short* Ab = smem + (kt & 3) * 16384;
    const unsigned short* Bb = Ab + 8192;
    short8 a[8], b[4];
#pragma unroll
    for (int i = 0; i < 8; i++)
      a[i] = *(const short8*)(Ab + (wr * 128 + i * 16 + fr) * 32 + csw);
#pragma unroll
    for (int j = 0; j < 4; j++)
      b[j] = *(const short8*)(Bb + (wc * 64 + j * 16 + fr) * 32 + csw);
    if (kt < 83) { stageA(kt + 3); stageB(kt + 3); }
    __builtin_amdgcn_s_setprio(1);
#pragma unroll
    for (int i = 0; i < 8; i++)
#pragma unroll
      for (int j = 0; j < 4; j++)
        acc[i][j] = __builtin_amdgcn_mfma_f32_16x16x32_bf16(a[i], b[j], acc[i][j], 0, 0, 0);
    __builtin_amdgcn_s_setprio(0);
  }

#pragma unroll
  for (int i = 0; i < 8; i++) {
#pragma unroll
    for (int j = 0; j < 4; j++) {
      const int col = n0 + wc * 64 + j * 16 + fr;
#pragma unroll
      for (int r2 = 0; r2 < 4; r2++) {
        const int row = m0 + wr * 128 + i * 16 + fq * 4 + r2;
        contrib[((size_t)e * CAP + row) * DMODEL + col] = f2bf(acc[i][j][r2]);
      }
    }
  }
}

// ---------------- Combine: out[tok] = g0*contrib[e0][s0] + g1*contrib[e1][s1] ----------------
__global__ void combine_kernel(const unsigned short* __restrict__ contrib,
                               const int* __restrict__ topi,
                               const int* __restrict__ slot,
                               const float* __restrict__ gates,
                               float* __restrict__ out) {
  const int tok = blockIdx.x;
  const int t = threadIdx.x;
  const int e0 = topi[2 * tok], e1 = topi[2 * tok + 1];
  const int s0 = slot[2 * tok], s1 = slot[2 * tok + 1];
  const float g0 = gates[2 * tok], g1 = gates[2 * tok + 1];
  float4 acc = make_float4(0.f, 0.f, 0.f, 0.f);
  if (s0 >= 0) {
    ushort4 c = *(const ushort4*)(contrib + ((size_t)(e0 * CAP + s0)) * DMODEL + t * 4);
    acc.x += g0 * bf2f(c.x); acc.y += g0 * bf2f(c.y);
    acc.z += g0 * bf2f(c.z); acc.w += g0 * bf2f(c.w);
  }
  if (s1 >= 0) {
    ushort4 c = *(const ushort4*)(contrib + ((size_t)(e1 * CAP + s1)) * DMODEL + t * 4);
    acc.x += g1 * bf2f(c.x); acc.y += g1 * bf2f(c.y);
    acc.z += g1 * bf2f(c.z); acc.w += g1 * bf2f(c.w);
  }
  *(float4*)(out + (size_t)tok * DMODEL + t * 4) = acc;
}

// ---------------- launch ----------------
extern "C" void kernel_launch(void* const* d_in, const int* in_sizes, int n_in,
                              void* d_out, int out_size, void* d_ws, size_t ws_size,
                              hipStream_t stream) {
  const float* x = (const float*)d_in[0];
  const float* noise = (const float*)d_in[1];
  const float* w_route = (const float*)d_in[2];
  const float* b_route = (const float*)d_in[3];
  const float* w_noise = (const float*)d_in[4];
  const float* b_noise = (const float*)d_in[5];
  const float* w_proj = (const float*)d_in[6];
  const float* w_down = (const float*)d_in[7];
  float* out = (float*)d_out;

  char* ws = (char*)d_ws;
  const size_t WT_BYTES = (size_t)NEXP * HFF2 * DMODEL * 2;   // 89.4 MB (wpT; later wdT+contrib)
  const size_t WDT_BYTES = (size_t)NEXP * DMODEL * KPAD * 2;  // 45.1 MB
  const size_t H_BYTES = (size_t)NEXP * CAP * KPAD * 2;       // 90.2 MB
  unsigned short* wT = (unsigned short*)ws;
  unsigned short* contrib = (unsigned short*)(ws + WDT_BYTES);  // 33.5 MB, dead tail of wT region
  unsigned short* hbuf = (unsigned short*)(ws + WT_BYTES);
  char* p = ws + WT_BYTES + H_BYTES;
  int* sel = (int*)p;          p += (size_t)NEXP * CAP * 4;
  float* gsel = (float*)p;     p += (size_t)NEXP * CAP * 4;
  int* topi = (int*)p;         p += (size_t)NTOK * 2 * 4;
  float* gates = (float*)p;    p += (size_t)NTOK * 2 * 4;
  int* slot = (int*)p;

  // xb (bf16 x, 16.8 MB) lives in d_out until gemm1 done; combine overwrites out fully.
  unsigned short* xb = (unsigned short*)d_out;

  hipLaunchKernelGGL(cast_x_kernel, dim3(NTOK * DMODEL / (256 * 8)), dim3(256), 0, stream, x, xb);
  hipLaunchKernelGGL(router_kernel, dim3(NTOK / 4), dim3(256), 0, stream,
                     x, noise, w_route, b_route, w_noise, b_noise, topi, gates);
  hipLaunchKernelGGL(dispatch_kernel, dim3(NEXP), dim3(1024), 0, stream, topi, gates, sel, gsel, slot);
  hipLaunchKernelGGL(transpose_wp_kernel, dim3(86, 16, NEXP), dim3(256), 0, stream, w_proj, wT);
  hipLaunchKernelGGL(gemm1_kernel, dim3(CAP / 256, 22, NEXP), dim3(512), 0, stream, xb, wT, sel, hbuf);
  hipLaunchKernelGGL(transpose_wd_kernel, dim3(KPAD / 32, DMODEL / 32, NEXP), dim3(256), 0, stream, w_down, wT);
  hipLaunchKernelGGL(gemm2_kernel, dim3(CAP / 256, DMODEL / 256, NEXP), dim3(512), 0, stream,
                     hbuf, wT, contrib);
  hipLaunchKernelGGL(combine_kernel, dim3(NTOK), dim3(256), 0, stream,
                     contrib, topi, slot, gates, out);
  hipLaunchKernelGGL(aux_kernel, dim3(1), dim3(256), 0, stream, topi, gates, out);
}